// Round 1
// baseline (361.455 us; speedup 1.0000x reference)
//
#include <hip/hip_runtime.h>

#define IN_CH  64
#define OUT_CH 32
#define BLOCK  8

// ws header (ints): [0..8]=cnt[9], [16..25]=off[10], [32..40]=cur[9]
// layout: hdr 256B | argmax M*4 | bm M*4 | bn M*4 | Wt 64KB

__global__ void k_transpose(const float* __restrict__ w, float* __restrict__ wt) {
    int d = blockIdx.x * 256 + threadIdx.x;
    if (d >= BLOCK * OUT_CH * IN_CH) return;
    // Wt float layout: [c4][j][o][e], c4=c/4, e=c%4
    int e  = d & 3;
    int o  = (d >> 2) & 31;
    int j  = (d >> 7) & 7;
    int c4 = d >> 10;
    int c  = c4 * 4 + e;
    wt[d] = w[(o * BLOCK + j) * IN_CH + c];
}

__global__ void k_scatter_max(const int* __restrict__ pair, int* __restrict__ argmax, int total) {
    int t = blockIdx.x * 256 + threadIdx.x;
    if (t >= total) return;
    int v = pair[t];
    if (v >= 0) atomicMax(&argmax[v], t);   // last-write-wins == max flat index
}

__global__ void k_hist(const int* __restrict__ argmax, int* __restrict__ hdr, int M, int N) {
    __shared__ int h[9];
    if (threadIdx.x < 9) h[threadIdx.x] = 0;
    __syncthreads();
    int m = blockIdx.x * 256 + threadIdx.x;
    if (m < M) {
        int t = argmax[m];
        int j = (t < 0) ? 8 : (int)((unsigned)t / (unsigned)N);
        atomicAdd(&h[j], 1);
    }
    __syncthreads();
    if (threadIdx.x < 9 && h[threadIdx.x] > 0) atomicAdd(&hdr[threadIdx.x], h[threadIdx.x]);
}

__global__ void k_prefix(int* hdr) {
    int acc = 0;
    for (int j = 0; j < 9; ++j) {
        hdr[16 + j] = acc;   // off
        hdr[32 + j] = acc;   // cur
        acc += hdr[j];
    }
    hdr[25] = acc;
}

__global__ void k_fill(const int* __restrict__ argmax, int* __restrict__ hdr,
                       int* __restrict__ bm, int* __restrict__ bn, int M, int N) {
    __shared__ int h[9];
    __shared__ int base[9];
    if (threadIdx.x < 9) h[threadIdx.x] = 0;
    __syncthreads();
    int m = blockIdx.x * 256 + threadIdx.x;
    int j = 8, lo = 0, n = 0;
    if (m < M) {
        int t = argmax[m];
        if (t >= 0) { j = (int)((unsigned)t / (unsigned)N); n = t - j * N; }
        lo = atomicAdd(&h[j], 1);
    }
    __syncthreads();
    if (threadIdx.x < 9)
        base[threadIdx.x] = (h[threadIdx.x] > 0) ? atomicAdd(&hdr[32 + threadIdx.x], h[threadIdx.x]) : 0;
    __syncthreads();
    if (m < M) {
        int pos = base[j] + lo;
        bm[pos] = m;
        bn[pos] = n;
    }
}

__global__ __launch_bounds__(256) void k_compute(
        const float* __restrict__ x, const float4* __restrict__ wt,
        const int* __restrict__ hdr, const int* __restrict__ bm,
        const int* __restrict__ bn, float* __restrict__ out) {
    int lane = threadIdx.x & 63;
    int o    = lane & 31;
    int h    = lane >> 5;
    int g    = (blockIdx.x * blockDim.x + threadIdx.x) >> 6;  // global wave id
    int b    = g & 7;                                          // bucket = kernel pos j
    int sub  = g >> 3;
    int nsub = (gridDim.x * blockDim.x) >> 9;                  // waves per bucket

    int cb   = hdr[b];
    int offb = hdr[16 + b];

    // W[o][b][c] for this lane's 32-c half, in registers (8 x float4)
    float4 w[8];
#pragma unroll
    for (int k = 0; k < 8; ++k)
        w[k] = wt[((h * 8 + k) * 8 + b) * 32 + o];

    for (int i = sub; i < cb; i += nsub) {
        int m = bm[offb + i];
        int n = bn[offb + i];
        const float4* xr = (const float4*)(x + (size_t)n * IN_CH) + h * 8;
        float4 a = make_float4(0.f, 0.f, 0.f, 0.f);
#pragma unroll
        for (int k = 0; k < 8; ++k) {
            float4 xv = xr[k];                 // same addr across o-lanes: broadcast
            a.x = fmaf(w[k].x, xv.x, a.x);
            a.y = fmaf(w[k].y, xv.y, a.y);
            a.z = fmaf(w[k].z, xv.z, a.z);
            a.w = fmaf(w[k].w, xv.w, a.w);
        }
        float s = (a.x + a.y) + (a.z + a.w);
        s += __shfl_xor(s, 32);                // combine the two c-halves
        if (h == 0) out[(size_t)m * OUT_CH + o] = s;
    }
}

__global__ void k_zero_invalid(const int* __restrict__ hdr, const int* __restrict__ bm,
                               float* __restrict__ out) {
    int cnt8 = hdr[8];
    int off8 = hdr[24];
    int total = cnt8 * OUT_CH;
    for (int e = blockIdx.x * 256 + threadIdx.x; e < total; e += gridDim.x * 256) {
        int i = e >> 5, o = e & 31;
        int m = bm[off8 + i];
        out[(size_t)m * OUT_CH + o] = 0.f;
    }
}

extern "C" void kernel_launch(void* const* d_in, const int* in_sizes, int n_in,
                              void* d_out, int out_size, void* d_ws, size_t ws_size,
                              hipStream_t stream) {
    const float* x    = (const float*)d_in[0];
    const float* w    = (const float*)d_in[1];
    const int*   pair = (const int*)d_in[2];
    int N = in_sizes[0] / IN_CH;     // 400000
    int M = out_size / OUT_CH;       // 200000
    int total = BLOCK * N;

    char* ws    = (char*)d_ws;
    int*  hdr   = (int*)ws;
    int*  argmax= (int*)(ws + 256);
    int*  bm    = (int*)(ws + 256 + (size_t)M * 4);
    int*  bn    = (int*)(ws + 256 + (size_t)M * 8);
    float* wt   = (float*)(ws + 256 + (size_t)M * 12);  // 16-byte aligned

    hipMemsetAsync(hdr, 0, 256, stream);
    hipMemsetAsync(argmax, 0xFF, (size_t)M * 4, stream);   // -1

    k_transpose  <<<(BLOCK * OUT_CH * IN_CH + 255) / 256, 256, 0, stream>>>(w, wt);
    k_scatter_max<<<(total + 255) / 256, 256, 0, stream>>>(pair, argmax, total);
    k_hist       <<<(M + 255) / 256, 256, 0, stream>>>(argmax, hdr, M, N);
    k_prefix     <<<1, 1, 0, stream>>>(hdr);
    k_fill       <<<(M + 255) / 256, 256, 0, stream>>>(argmax, hdr, bm, bn, M, N);
    k_compute    <<<2048, 256, 0, stream>>>(x, (const float4*)wt, hdr, bm, bn, (float*)d_out);
    k_zero_invalid<<<64, 256, 0, stream>>>(hdr, bm, (float*)d_out);
}

// Round 2
// 210.854 us; speedup vs baseline: 1.7142x; 1.7142x over previous
//
#include <hip/hip_runtime.h>

#define IN_CH  64
#define OUT_CH 32
#define BLOCK  8

// ws layout: argmax M*4 | wt 64KB (16B aligned since M*4 % 16 == 0)

__global__ void k_transpose(const float* __restrict__ w, float* __restrict__ wt) {
    int d = blockIdx.x * 256 + threadIdx.x;
    if (d >= BLOCK * OUT_CH * IN_CH) return;
    // wt float layout: [c4][j][o][e]  (c4 = c/4 in 0..15, e = c%4)
    int e  = d & 3;
    int o  = (d >> 2) & 31;
    int j  = (d >> 7) & 7;
    int c4 = d >> 10;
    int c  = c4 * 4 + e;
    wt[d] = w[(o * BLOCK + j) * IN_CH + c];
}

__global__ void k_scatter_max(const int* __restrict__ pair, int* __restrict__ argmax, int total) {
    int t = blockIdx.x * 256 + threadIdx.x;
    if (t >= total) return;
    int v = pair[t];
    if (v >= 0) atomicMax(&argmax[v], t);   // last-write-wins == max flat index
}

struct XRow { float4 v[8]; };

__device__ __forceinline__ XRow load_x(const float* __restrict__ x, int t, unsigned N, int h) {
    XRow r;
    int n = 0;
    if (t >= 0) {
        unsigned j = (unsigned)t / N;
        n = t - (int)(j * N);
    }
    const float4* xr = (const float4*)(x + (size_t)n * IN_CH) + h * 8;
#pragma unroll
    for (int k = 0; k < 8; ++k) r.v[k] = xr[k];
    return r;
}

__device__ __forceinline__ float dot_row(const float4* __restrict__ lds, int t, unsigned N,
                                         int o, int h, const XRow& xr) {
    if (t < 0) return 0.f;
    int j = (int)((unsigned)t / N);
    // float4 index for k: (h*8+k)*256 + j*32 + o  -> base + k*256
    const float4* wp = lds + h * 2048 + j * 32 + o;
    float4 a = make_float4(0.f, 0.f, 0.f, 0.f);
#pragma unroll
    for (int k = 0; k < 8; ++k) {
        float4 wv = wp[k * 256];
        float4 xv = xr.v[k];
        a.x = fmaf(wv.x, xv.x, a.x);
        a.y = fmaf(wv.y, xv.y, a.y);
        a.z = fmaf(wv.z, xv.z, a.z);
        a.w = fmaf(wv.w, xv.w, a.w);
    }
    float s = (a.x + a.y) + (a.z + a.w);
    s += __shfl_xor(s, 32);                // combine the two c-halves
    return s;
}

__global__ __launch_bounds__(512, 4) void k_compute(
        const float* __restrict__ x, const float4* __restrict__ wt,
        const int* __restrict__ argmax, float* __restrict__ out, int M, int N) {
    __shared__ float4 Wl[4096];            // 64 KB: full weight tensor
    for (int i = threadIdx.x; i < 4096; i += 512) Wl[i] = wt[i];
    __syncthreads();

    int lane = threadIdx.x & 63;
    int o    = lane & 31;
    int h    = lane >> 5;
    int gw   = (blockIdx.x * 512 + threadIdx.x) >> 6;
    int nw   = (gridDim.x * 512) >> 6;
    unsigned uN = (unsigned)N;

    for (int base = gw * 64; base < M; base += nw * 64) {
        int mrow  = base + lane;
        int t64   = (mrow < M) ? argmax[mrow] : -1;   // coalesced meta-load
        int nrows = min(64, M - base);
        for (int r = 0; r < nrows; r += 2) {
            int t0 = __shfl(t64, r);
            int t1 = (r + 1 < nrows) ? __shfl(t64, r + 1) : -1;
            XRow xa = load_x(x, t0, uN, h);           // both rows' loads in flight
            XRow xb = load_x(x, t1, uN, h);
            float s0 = dot_row(Wl, t0, uN, o, h, xa);
            float s1 = dot_row(Wl, t1, uN, o, h, xb);
            // full-wave coalesced store: h=0 lanes -> row r, h=1 lanes -> row r+1
            float sv = h ? s1 : s0;
            if (r + h < nrows)
                out[(size_t)(base + r + h) * OUT_CH + o] = sv;
        }
    }
}

extern "C" void kernel_launch(void* const* d_in, const int* in_sizes, int n_in,
                              void* d_out, int out_size, void* d_ws, size_t ws_size,
                              hipStream_t stream) {
    const float* x    = (const float*)d_in[0];
    const float* w    = (const float*)d_in[1];
    const int*   pair = (const int*)d_in[2];
    int N = in_sizes[0] / IN_CH;     // 400000
    int M = out_size / OUT_CH;       // 200000
    int total = BLOCK * N;

    char*  ws     = (char*)d_ws;
    int*   argmax = (int*)ws;
    float* wt     = (float*)(ws + (size_t)M * 4);

    hipMemsetAsync(argmax, 0xFF, (size_t)M * 4, stream);   // -1

    k_transpose  <<<(BLOCK * OUT_CH * IN_CH + 255) / 256, 256, 0, stream>>>(w, wt);
    k_scatter_max<<<(total + 255) / 256, 256, 0, stream>>>(pair, argmax, total);
    k_compute    <<<512, 512, 0, stream>>>(x, (const float4*)wt, argmax,
                                           (float*)d_out, M, N);
}

// Round 3
// 133.466 us; speedup vs baseline: 2.7082x; 1.5798x over previous
//
#include <hip/hip_runtime.h>

#define IN_CH  64
#define OUT_CH 32
#define BLOCK  8

// ws layout: argmax M*4 | wt 64KB (16B aligned since M*4 % 16 == 0)

__global__ void k_transpose(const float* __restrict__ w, float* __restrict__ wt) {
    int d = blockIdx.x * 256 + threadIdx.x;
    if (d >= BLOCK * OUT_CH * IN_CH) return;
    // wt float layout: [c4][j][o][e]  (c4 = c/4 in 0..15, e = c%4)
    int e  = d & 3;
    int o  = (d >> 2) & 31;
    int j  = (d >> 7) & 7;
    int c4 = d >> 10;
    int c  = c4 * 4 + e;
    wt[d] = w[(o * BLOCK + j) * IN_CH + c];
}

// argmax[m] is monotone non-decreasing, so a stale (L2-cached) read is a valid
// lower bound: skipping when argmax[m] >= t is ALWAYS correct, and atomicMax
// handles any race we don't skip. Dispatch boundaries make prior dispatches'
// atomics visible to the plain filter reads, so later passes filter ~hard.
__global__ void k_scatter_range(const int* __restrict__ pair, int* __restrict__ argmax,
                                int N, int jhi, int jlo, int flip) {
    int n = blockIdx.x * 256 + threadIdx.x;
    if (n >= N) return;
    if (flip) n = N - 1 - n;        // high-t first (execution order ~ blockIdx)
    for (int j = jhi; j >= jlo; --j) {
        int t = j * N + n;
        int m = pair[t];
        if (m >= 0 && argmax[m] < t)
            atomicMax(&argmax[m], t);
    }
}

struct XRow { float4 v[8]; };

__device__ __forceinline__ XRow load_x(const float* __restrict__ x, int t, unsigned N, int h) {
    XRow r;
    int n = 0;
    if (t >= 0) {
        unsigned j = (unsigned)t / N;
        n = t - (int)(j * N);
    }
    const float4* xr = (const float4*)(x + (size_t)n * IN_CH) + h * 8;
#pragma unroll
    for (int k = 0; k < 8; ++k) r.v[k] = xr[k];
    return r;
}

__device__ __forceinline__ float dot_row(const float4* __restrict__ lds, int t, unsigned N,
                                         int o, int h, const XRow& xr) {
    if (t < 0) return 0.f;
    int j = (int)((unsigned)t / N);
    // float4 index for k: (h*8+k)*256 + j*32 + o  -> base + k*256
    const float4* wp = lds + h * 2048 + j * 32 + o;
    float4 a = make_float4(0.f, 0.f, 0.f, 0.f);
#pragma unroll
    for (int k = 0; k < 8; ++k) {
        float4 wv = wp[k * 256];
        float4 xv = xr.v[k];
        a.x = fmaf(wv.x, xv.x, a.x);
        a.y = fmaf(wv.y, xv.y, a.y);
        a.z = fmaf(wv.z, xv.z, a.z);
        a.w = fmaf(wv.w, xv.w, a.w);
    }
    float s = (a.x + a.y) + (a.z + a.w);
    s += __shfl_xor(s, 32);                // combine the two c-halves
    return s;
}

__global__ __launch_bounds__(512, 4) void k_compute(
        const float* __restrict__ x, const float4* __restrict__ wt,
        const int* __restrict__ argmax, float* __restrict__ out, int M, int N) {
    __shared__ float4 Wl[4096];            // 64 KB: full weight tensor
    for (int i = threadIdx.x; i < 4096; i += 512) Wl[i] = wt[i];
    __syncthreads();

    int lane = threadIdx.x & 63;
    int o    = lane & 31;
    int h    = lane >> 5;
    int gw   = (blockIdx.x * 512 + threadIdx.x) >> 6;
    int nw   = (gridDim.x * 512) >> 6;
    unsigned uN = (unsigned)N;

    for (int base = gw * 64; base < M; base += nw * 64) {
        int mrow  = base + lane;
        int t64   = (mrow < M) ? argmax[mrow] : -1;   // coalesced meta-load
        int nrows = min(64, M - base);
        for (int r = 0; r < nrows; r += 2) {
            int t0 = __shfl(t64, r);
            int t1 = (r + 1 < nrows) ? __shfl(t64, r + 1) : -1;
            XRow xa = load_x(x, t0, uN, h);           // both rows' loads in flight
            XRow xb = load_x(x, t1, uN, h);
            float s0 = dot_row(Wl, t0, uN, o, h, xa);
            float s1 = dot_row(Wl, t1, uN, o, h, xb);
            // full-wave coalesced store: h=0 lanes -> row r, h=1 lanes -> row r+1
            float sv = h ? s1 : s0;
            if (r + h < nrows)
                out[(size_t)(base + r + h) * OUT_CH + o] = sv;
        }
    }
}

extern "C" void kernel_launch(void* const* d_in, const int* in_sizes, int n_in,
                              void* d_out, int out_size, void* d_ws, size_t ws_size,
                              hipStream_t stream) {
    const float* x    = (const float*)d_in[0];
    const float* w    = (const float*)d_in[1];
    const int*   pair = (const int*)d_in[2];
    int N = in_sizes[0] / IN_CH;     // 400000
    int M = out_size / OUT_CH;       // 200000

    char*  ws     = (char*)d_ws;
    int*   argmax = (int*)ws;
    float* wt     = (float*)(ws + (size_t)M * 4);

    hipMemsetAsync(argmax, 0xFF, (size_t)M * 4, stream);   // -1

    int gN = (N + 255) / 256;
    k_transpose    <<<(BLOCK * OUT_CH * IN_CH + 255) / 256, 256, 0, stream>>>(w, wt);
    k_scatter_range<<<gN, 256, 0, stream>>>(pair, argmax, N, 7, 7, 1); // j=7, high-t first
    k_scatter_range<<<gN, 256, 0, stream>>>(pair, argmax, N, 6, 6, 0); // j=6, sees j=7
    k_scatter_range<<<gN, 256, 0, stream>>>(pair, argmax, N, 5, 0, 0); // rest, ~98% filtered
    k_compute      <<<512, 512, 0, stream>>>(x, (const float4*)wt, argmax,
                                             (float*)d_out, M, N);
}

// Round 4
// 131.638 us; speedup vs baseline: 2.7458x; 1.0139x over previous
//
#include <hip/hip_runtime.h>

#define IN_CH  64
#define OUT_CH 32
#define BLOCK  8

// ws layout: argmax M*4 | wt(bf16) 32KB

// wt bf16 layout: u32 index = ((c4*8 + j)*32 + o)*2 + p
// each u32 holds bf16 pair for channels (c4*4 + 2p, c4*4 + 2p + 1)
__global__ void k_transpose_bf16(const float* __restrict__ w, unsigned* __restrict__ wt) {
    int d = blockIdx.x * 256 + threadIdx.x;          // 8192 u32 words
    if (d >= BLOCK * OUT_CH * IN_CH / 2) return;
    int p  = d & 1;
    int o  = (d >> 1) & 31;
    int j  = (d >> 6) & 7;
    int c4 = d >> 9;
    int c  = c4 * 4 + p * 2;
    float f0 = w[(o * BLOCK + j) * IN_CH + c];
    float f1 = w[(o * BLOCK + j) * IN_CH + c + 1];
    auto cvt = [](float f) -> unsigned {             // RN-even f32 -> bf16
        unsigned u = __float_as_uint(f);
        return (u + 0x7fffu + ((u >> 16) & 1u)) >> 16;
    };
    wt[d] = cvt(f0) | (cvt(f1) << 16);
}

// argmax[m] is monotone non-decreasing, so a stale (L2-cached) read is a valid
// lower bound: skipping when argmax[m] >= t is ALWAYS correct; atomicMax
// handles any race we don't skip. Dispatch boundaries make prior dispatches'
// atomics visible to the plain filter reads, so later passes filter ~hard.
__global__ void k_scatter_range(const int* __restrict__ pair, int* __restrict__ argmax,
                                int N, int jhi, int jlo, int flip) {
    int n = blockIdx.x * 256 + threadIdx.x;
    if (n >= N) return;
    if (flip) n = N - 1 - n;        // high-t first (execution order ~ blockIdx)
    for (int j = jhi; j >= jlo; --j) {
        int t = j * N + n;
        int m = pair[t];
        if (m >= 0 && argmax[m] < t)
            atomicMax(&argmax[m], t);
    }
}

__global__ __launch_bounds__(512, 8) void k_compute(
        const float* __restrict__ x, const uint2* __restrict__ wt,
        const int* __restrict__ argmax, float* __restrict__ out, int M, int N) {
    __shared__ uint2 Wl[4096];                       // 32 KB: full weights, bf16
    for (int i = threadIdx.x; i < 4096; i += 512) Wl[i] = wt[i];
    __syncthreads();

    int lane = threadIdx.x & 63;
    int o    = lane & 31;
    int h    = lane >> 5;
    int gw   = (blockIdx.x * 512 + threadIdx.x) >> 6;   // global wave id
    unsigned uN = (unsigned)N;

    int base = gw * 32;
    if (base >= M) return;
    int nrows = min(32, M - base);

    int t64 = (lane < nrows) ? argmax[base + lane] : -1;   // coalesced meta-load

    for (int r = 0; r < nrows; ++r) {
        int t = __shfl(t64, r);
        float s = 0.f;
        if (t >= 0) {
            unsigned j = (unsigned)t / uN;
            int n = t - (int)(j * uN);
            const float4* xr = (const float4*)(x + (size_t)n * IN_CH) + h * 8;
            float4 xv[8];
#pragma unroll
            for (int k = 0; k < 8; ++k) xv[k] = xr[k];   // 8 loads in flight
            const uint2* wp = Wl + ((h * 8) * 8 + (int)j) * 32 + o;
            float4 a = make_float4(0.f, 0.f, 0.f, 0.f);
#pragma unroll
            for (int k = 0; k < 8; ++k) {
                uint2 wv = wp[k * 256];                  // +k on c4 -> +8*32 uint2
                float w0 = __uint_as_float(wv.x << 16);
                float w1 = __uint_as_float(wv.x & 0xffff0000u);
                float w2 = __uint_as_float(wv.y << 16);
                float w3 = __uint_as_float(wv.y & 0xffff0000u);
                a.x = fmaf(w0, xv[k].x, a.x);
                a.y = fmaf(w1, xv[k].y, a.y);
                a.z = fmaf(w2, xv[k].z, a.z);
                a.w = fmaf(w3, xv[k].w, a.w);
            }
            s = (a.x + a.y) + (a.z + a.w);
            s += __shfl_xor(s, 32);                      // combine c-halves
        }
        if (h == 0)
            out[(size_t)(base + r) * OUT_CH + o] = s;
    }
}

extern "C" void kernel_launch(void* const* d_in, const int* in_sizes, int n_in,
                              void* d_out, int out_size, void* d_ws, size_t ws_size,
                              hipStream_t stream) {
    const float* x    = (const float*)d_in[0];
    const float* w    = (const float*)d_in[1];
    const int*   pair = (const int*)d_in[2];
    int N = in_sizes[0] / IN_CH;     // 400000
    int M = out_size / OUT_CH;       // 200000

    char*     ws     = (char*)d_ws;
    int*      argmax = (int*)ws;
    unsigned* wt     = (unsigned*)(ws + (size_t)M * 4);

    hipMemsetAsync(argmax, 0xFF, (size_t)M * 4, stream);   // -1

    int gN = (N + 255) / 256;
    k_transpose_bf16<<<(BLOCK * OUT_CH * IN_CH / 2 + 255) / 256, 256, 0, stream>>>(w, wt);
    k_scatter_range<<<gN, 256, 0, stream>>>(pair, argmax, N, 7, 7, 1); // j=7, high-t first
    k_scatter_range<<<gN, 256, 0, stream>>>(pair, argmax, N, 6, 6, 0); // j=6, sees j=7
    k_scatter_range<<<gN, 256, 0, stream>>>(pair, argmax, N, 5, 0, 0); // rest, ~98% filtered

    int waves  = (M + 31) / 32;
    int blocks = (waves + 7) / 8;
    k_compute<<<blocks, 512, 0, stream>>>(x, (const uint2*)wt, argmax,
                                          (float*)d_out, M, N);
}